// Round 16
// baseline (274.943 us; speedup 1.0000x reference)
//
#include <hip/hip_runtime.h>
#include <hip/hip_bf16.h>

// MultiHeadDotProductAttention: b=4, L=2048, E=1024, H=16, D=64
// R16: T15 retry with root-caused fix. Iter t: QK(t) [MFMA] -> PV(t-1)
// [MFMA, carried P-fragments pfr (16 VGPR, not 64) + V(t-1)] -> SM(t)
// [VALU/exp, overlaps PV drain] -> new pfr. No __launch_bounds__ pin
// (R14's spill source). V triple-buffered, K double-buffered, 1
// barrier/tile. Math order-identical to R15. GEMM/cast/wtrans unchanged.

typedef __attribute__((ext_vector_type(8))) short bf16x8;
typedef __attribute__((ext_vector_type(2))) float f32x2;
typedef __attribute__((ext_vector_type(4))) float f32x4;
typedef __attribute__((ext_vector_type(16))) float f32x16;

#define MFMA16(a, b, c) __builtin_amdgcn_mfma_f32_16x16x32_bf16((a), (b), (c), 0, 0, 0)
#define MFMA32(a, b, c) __builtin_amdgcn_mfma_f32_32x32x16_bf16((a), (b), (c), 0, 0, 0)

__device__ __forceinline__ short f2bf(float f) {
  union { float f; unsigned u; } v; v.f = f;
  unsigned r = v.u + 0x7fffu + ((v.u >> 16) & 1u);  // RNE
  return (short)(r >> 16);
}

__device__ __forceinline__ unsigned cvtpk(float lo, float hi) {
  unsigned r;
  asm("v_cvt_pk_bf16_f32 %0, %1, %2" : "=v"(r) : "v"(lo), "v"(hi));
  return r;
}

__device__ __forceinline__ void plswap(unsigned& a, unsigned& b) {
  asm volatile("v_permlane32_swap_b32 %0, %1" : "+v"(a), "+v"(b));
}

// Cross-half (lane i <-> i+32) reduce via the permlane32_swap BUILTIN
// (compiler-managed hazards; opaque-asm version raced a VALU->permlane
// wait-state, R9). Empty-asm pin keeps operand 2 in its own register.
#if __has_builtin(__builtin_amdgcn_permlane32_swap)
typedef __attribute__((ext_vector_type(2))) unsigned u32x2;
__device__ __forceinline__ float xhalf_max(float x) {
  float y = x;
  asm("" : "+v"(y));
  const u32x2 r = __builtin_amdgcn_permlane32_swap(
      __float_as_uint(x), __float_as_uint(y), false, false);
  return fmaxf(__uint_as_float(r[0]), __uint_as_float(r[1]));
}
__device__ __forceinline__ float xhalf_add(float x) {
  float y = x;
  asm("" : "+v"(y));
  const u32x2 r = __builtin_amdgcn_permlane32_swap(
      __float_as_uint(x), __float_as_uint(y), false, false);
  return __uint_as_float(r[0]) + __uint_as_float(r[1]);
}
#else
__device__ __forceinline__ float xhalf_max(float x) {
  float a, b;
  asm volatile(
      "v_mov_b32 %0, %2\n\tv_mov_b32 %1, %2\n\ts_nop 2\n\t"
      "v_permlane32_swap_b32 %0, %1"
      : "=&v"(a), "=&v"(b) : "v"(x));
  return fmaxf(a, b);
}
__device__ __forceinline__ float xhalf_add(float x) {
  float a, b;
  asm volatile(
      "v_mov_b32 %0, %2\n\tv_mov_b32 %1, %2\n\ts_nop 2\n\t"
      "v_permlane32_swap_b32 %0, %1"
      : "=&v"(a), "=&v"(b) : "v"(x));
  return a + b;
}
#endif

__device__ __forceinline__ void gld16(const short* g, short* l) {
  __builtin_amdgcn_global_load_lds(
      (const __attribute__((address_space(1))) unsigned int*)g,
      (__attribute__((address_space(3))) unsigned int*)l, 16, 0, 0);
}

// ---------------------------------------------------------------------------
// f32 -> bf16 cast, both inputs in one launch (z selects buffer), RNE.
// ---------------------------------------------------------------------------
__global__ __launch_bounds__(256) void cast2_kernel(
    const float* __restrict__ in0, short* __restrict__ out0,
    const float* __restrict__ in1, short* __restrict__ out1, int n8) {
  const float* in = blockIdx.y ? in1 : in0;
  short* out = blockIdx.y ? out1 : out0;
  int i = blockIdx.x * 256 + threadIdx.x;
  const int stride = gridDim.x * 256;
  for (; i < n8; i += stride) {
    const float4 f0 = ((const float4*)in)[2 * i];
    const float4 f1 = ((const float4*)in)[2 * i + 1];
    bf16x8 v;
    v[0] = f2bf(f0.x); v[1] = f2bf(f0.y); v[2] = f2bf(f0.z); v[3] = f2bf(f0.w);
    v[4] = f2bf(f1.x); v[5] = f2bf(f1.y); v[6] = f2bf(f1.z); v[7] = f2bf(f1.w);
    ((bf16x8*)out)[i] = v;
  }
}

// ---------------------------------------------------------------------------
// Weight transpose + convert: W[k][n] f32 (1024x1024) -> WT[n][k] bf16 (RNE).
// ---------------------------------------------------------------------------
__global__ __launch_bounds__(256) void wtrans_kernel(
    const float* __restrict__ w0, const float* __restrict__ w1,
    const float* __restrict__ w2, const float* __restrict__ w3,
    short* __restrict__ out) {
  __shared__ float t[32][33];
  const int z = blockIdx.z;
  const float* src = (z == 0) ? w0 : (z == 1) ? w1 : (z == 2) ? w2 : w3;
  short* dst = out + (size_t)z * (1024 * 1024);
  const int x = threadIdx.x & 31, y = threadIdx.x >> 5;
  const int n0 = blockIdx.x * 32, k0 = blockIdx.y * 32;
#pragma unroll
  for (int yy = y; yy < 32; yy += 8)
    t[yy][x] = src[(size_t)(k0 + yy) * 1024 + n0 + x];
  __syncthreads();
#pragma unroll
  for (int yy = y; yy < 32; yy += 8)
    dst[(size_t)(n0 + yy) * 1024 + k0 + x] = f2bf(t[x][yy]);
}

// ---------------------------------------------------------------------------
// GEMM core (m97 structure), shared by gemm_bb and gemm_qk.
// ---------------------------------------------------------------------------
template <bool OUTF32>
__device__ __forceinline__ void gemm_body(
    const short* __restrict__ A, const short* __restrict__ B,
    void* __restrict__ Cp, int K, int ldc, float scale, int m0, int n0,
    short (*At)[64], short (*Bt)[64]) {
  const int tid = threadIdx.x, l = tid & 63, w = tid >> 6;
  const int wm = (w >> 1) * 64, wn = (w & 1) * 64;
  const short* Abase = A + (size_t)(m0 + w * 8 + (l >> 3)) * K + (l & 7) * 8;
  const short* Bbase = B + (size_t)(n0 + w * 8 + (l >> 3)) * K + (l & 7) * 8;

  f32x4 acc[4][4];
#pragma unroll
  for (int i = 0; i < 4; ++i)
#pragma unroll
    for (int j = 0; j < 4; ++j) acc[i][j] = (f32x4){0.f, 0.f, 0.f, 0.f};

  for (int k0 = 0; k0 < K; k0 += 64) {
    __syncthreads();
#pragma unroll
    for (int i = 0; i < 4; ++i) {
      gld16(Abase + (size_t)i * 32 * K + k0, &At[i * 32 + w * 8][0]);
      gld16(Bbase + (size_t)i * 32 * K + k0, &Bt[i * 32 + w * 8][0]);
    }
    __syncthreads();  // vmcnt(0) before s_barrier -> staged data ready
#pragma unroll
    for (int ks = 0; ks < 2; ++ks) {
      bf16x8 af[4], bfr[4];
#pragma unroll
      for (int mt = 0; mt < 4; ++mt)
        af[mt] = *(const bf16x8*)&At[wm + mt * 16 + (l & 15)][ks * 32 + (l >> 4) * 8];
#pragma unroll
      for (int nt = 0; nt < 4; ++nt)
        bfr[nt] = *(const bf16x8*)&Bt[wn + nt * 16 + (l & 15)][ks * 32 + (l >> 4) * 8];
#pragma unroll
      for (int mt = 0; mt < 4; ++mt)
#pragma unroll
        for (int nt = 0; nt < 4; ++nt)
          acc[mt][nt] = MFMA16(af[mt], bfr[nt], acc[mt][nt]);
    }
  }
  // C/D layout: col = lane&15, row = (lane>>4)*4 + reg (m89)
#pragma unroll
  for (int mt = 0; mt < 4; ++mt)
#pragma unroll
    for (int nt = 0; nt < 4; ++nt)
#pragma unroll
      for (int r = 0; r < 4; ++r) {
        const int row = m0 + wm + mt * 16 + (l >> 4) * 4 + r;
        const int col = n0 + wn + nt * 16 + (l & 15);
        const float v = acc[mt][nt][r] * scale;
        if (OUTF32)
          ((float*)Cp)[(size_t)row * ldc + col] = v;
        else
          ((short*)Cp)[(size_t)row * ldc + col] = f2bf(v);
      }
}

// Generic GEMM (vT and out projections). SWZ: XCD-aware remap.
template <bool OUTF32, bool SWZ>
__global__ __launch_bounds__(256) void gemm_bb(
    const short* __restrict__ A, const short* __restrict__ B,
    void* __restrict__ Cp, int M, int N, int K, int ldc, float scale) {
  __shared__ __align__(16) short At[128][64];
  __shared__ __align__(16) short Bt[128][64];
  int bx = blockIdx.x, by = blockIdx.y;
  if (SWZ) {
    const int nbx = gridDim.x;
    const int lin = by * nbx + bx;
    const int cpx = (nbx * gridDim.y) >> 3;
    const int swz = (lin & 7) * cpx + (lin >> 3);
    bx = swz % nbx;
    by = swz / nbx;
  }
  gemm_body<OUTF32>(A, B, Cp, K, ldc, scale, by * 128, bx * 128, At, Bt);
}

// Fused q+k projections: grid (8,64,2); z=0 -> q (scaled), z=1 -> k.
// XCD swizzle over the full 1024-block grid.
__global__ __launch_bounds__(256) void gemm_qk(
    const short* __restrict__ Aq, const short* __restrict__ Ak,
    const short* __restrict__ Bq, const short* __restrict__ Bk,
    short* __restrict__ Cq, short* __restrict__ Ck, float scaleq) {
  __shared__ __align__(16) short At[128][64];
  __shared__ __align__(16) short Bt[128][64];
  const int lin = (blockIdx.z * 64 + blockIdx.y) * 8 + blockIdx.x;
  const int swz = (lin & 7) * 128 + (lin >> 3);
  const int bz = swz >> 9;  // / 512
  const int rem = swz & 511;
  const int by = rem >> 3, bx = rem & 7;
  const short* A = bz ? Ak : Aq;
  const short* B = bz ? Bk : Bq;
  short* C = bz ? Ck : Cq;
  const float scale = bz ? 1.0f : scaleq;
  gemm_body<false>(A, B, C, 1024, 1024, scale, by * 128, bx * 128, At, Bt);
}

// ---------------------------------------------------------------------------
// Flash attention, cross-tile pipelined (T15, fragment-carry form):
// iter t: QK(t) MFMA -> PV(t-1) MFMA (carried pfr + V[(t-1)%3]) -> SM(t)
// VALU/exp (overlaps PV drain) -> new pfr. 8 waves x 32 q-rows, KVBLK=64,
// defer-max, permlane reduces, packed-f32 softmax, XCD swizzle.
// K double-buffered; V triple-buffered (write slot (t+1)%3 at iter t; its
// last read was iter t-1, separated by the iter-t barrier).
// ---------------------------------------------------------------------------
__global__ __launch_bounds__(512) void attn8w_kernel(
    const short* __restrict__ qb, const short* __restrict__ kb,
    const short* __restrict__ vT, short* __restrict__ ob) {
  __shared__ __align__(16) short Ksh[2][64][64];
  __shared__ __align__(16) short Vsh[3][64][64];
  const int tid = threadIdx.x, w = tid >> 6, l = tid & 63;
  const int hi = l >> 5, ln = l & 31;
  // T1 swizzle: grid (8,64), nwg=512. XCD k gets bh in [8k, 8k+8).
  const int lin = blockIdx.y * 8 + blockIdx.x;
  const int swz = (lin & 7) * 64 + (lin >> 3);
  const int qc = swz & 7, bh = swz >> 3;
  const int b = bh >> 4, h = bh & 15;
  const size_t bL = (size_t)b * 2048;
  const int hd = h * 64;
  const int q0 = qc * 256 + w * 32;

  // staging: wave w stages rows w*8..w*8+7 of K and of V (1 gld16 each)
  const int sr0 = w * 8 + (l >> 3);
  const int sc0 = ((l & 7) ^ (sr0 & 7)) << 3;  // pre-swizzled source col
  const short* kbase = kb + (bL + sr0) * 1024 + hd + sc0;
  const short* vbase = vT + (size_t)(hd + sr0) * 8192 + bL + sc0;

#define SK(BUF, KV0) gld16(kbase + (size_t)(KV0) * 1024, &Ksh[BUF][w * 8][0])
#define SV(SLOT, KV0) gld16(vbase + (KV0), &Vsh[SLOT][w * 8][0])

  bf16x8 qf[4];
  {
    const short* qrow = qb + (bL + q0 + ln) * 1024 + hd + hi * 8;
#pragma unroll
    for (int c = 0; c < 4; ++c) qf[c] = *(const bf16x8*)(qrow + c * 16);
  }

  f32x16 o0, o1;
#pragma unroll
  for (int i = 0; i < 16; ++i) { o0[i] = 0.f; o1[i] = 0.f; }
  float m = -1e30f, lsum = 0.f;  // lsum lane-partial (combined at end)

  const int swzk = ln & 7;

// S^T = K . Q^T from Ksh[KSLOT] into (s0,s1)
#define QK(KSLOT)                                                            \
  do {                                                                       \
    const short(*Kt)[64] = Ksh[KSLOT];                                       \
    _Pragma("unroll") for (int i = 0; i < 16; ++i) { s0[i] = 0.f; s1[i] = 0.f; } \
    __builtin_amdgcn_s_setprio(1);                                           \
    _Pragma("unroll") for (int c = 0; c < 4; ++c) {                          \
      const int bcol = ((((c << 1) | hi)) ^ swzk) << 3;                      \
      const bf16x8 kf0 = *(const bf16x8*)&Kt[ln][bcol];                      \
      const bf16x8 kf1 = *(const bf16x8*)&Kt[32 + ln][bcol];                 \
      s0 = MFMA32(kf0, qf[c], s0);                                           \
      s1 = MFMA32(kf1, qf[c], s1);                                           \
    }                                                                        \
    __builtin_amdgcn_s_setprio(0);                                           \
  } while (0)

// O += P(prev) . V(prev) from carried pfr and Vsh[VSLOT]
#define PVFRAG(VSLOT)                                                        \
  do {                                                                       \
    const short(*Vt)[64] = Vsh[VSLOT];                                       \
    __builtin_amdgcn_s_setprio(1);                                           \
    _Pragma("unroll") for (int c = 0; c < 4; ++c) {                          \
      const int bcol = ((((c << 1) | hi)) ^ swzk) << 3;                      \
      const bf16x8 vf0 = *(const bf16x8*)&Vt[ln][bcol];                      \
      const bf16x8 vf1 = *(const bf16x8*)&Vt[32 + ln][bcol];                 \
      o0 = MFMA32(vf0, pfr[c], o0);                                          \
      o1 = MFMA32(vf1, pfr[c], o1);                                          \
    }                                                                        \
    __builtin_amdgcn_s_setprio(0);                                           \
  } while (0)

#define PACK8(PARR, BASE, DST)                                               \
  do {                                                                       \
    unsigned A0 = cvtpk(PARR[(BASE) + 0], PARR[(BASE) + 1]);                 \
    unsigned A1 = cvtpk(PARR[(BASE) + 2], PARR[(BASE) + 3]);                 \
    unsigned B0 = cvtpk(PARR[(BASE) + 4], PARR[(BASE) + 5]);                 \
    unsigned B1 = cvtpk(PARR[(BASE) + 6], PARR[(BASE) + 7]);                 \
    plswap(A0, B0);                                                          \
    plswap(A1, B1);                                                          \
    union { unsigned u[4]; bf16x8 v; } pf_;                                  \
    pf_.u[0] = A0; pf_.u[1] = A1; pf_.u[2] = B0; pf_.u[3] = B1;              \
    DST = pf_.v;                                                             \
  } while (0)

// softmax on (s0,s1): updates m/lsum (defer-max), packs P into pfr
#define SMGEN()                                                              \
  do {                                                                       \
    f32x2 pm0 = (f32x2){s0[0], s0[1]};                                       \
    f32x2 pm1 = (f32x2){s1[0], s1[1]};                                       \
    _Pragma("unroll") for (int i = 1; i < 8; ++i) {                          \
      pm0 = __builtin_elementwise_max(pm0, (f32x2){s0[2 * i], s0[2 * i + 1]}); \
      pm1 = __builtin_elementwise_max(pm1, (f32x2){s1[2 * i], s1[2 * i + 1]}); \
    }                                                                        \
    pm0 = __builtin_elementwise_max(pm0, pm1);                               \
    float pmax = fmaxf(pm0[0], pm0[1]);                                      \
    pmax = xhalf_max(pmax);                                                  \
    if (!__all(pmax - m <= 8.0f)) {                                          \
      const float mnew = fmaxf(m, pmax);                                     \
      const float fac = exp2f(m - mnew);                                     \
      m = mnew;                                                              \
      lsum *= fac;                                                           \
      o0 *= fac;                                                             \
      o1 *= fac;                                                             \
    }                                                                        \
    float p0[16], p1[16];                                                    \
    const f32x2 m2 = (f32x2){m, m};                                          \
    f32x2 acc2 = (f32x2){0.f, 0.f};                                          \
    _Pragma("unroll") for (int i = 0; i < 8; ++i) {                          \
      const f32x2 d0 = (f32x2){s0[2 * i], s0[2 * i + 1]} - m2;               \
      const f32x2 d1 = (f32x2){s1[2 * i], s1[2 * i + 1]} - m2;               \
      p0[2 * i] = exp2f(d0[0]);                                              \
      p0[2 * i + 1] = exp2f(d0[1]);                                          \
      p1[2 * i] = exp2f(d1[0]);                                              \
      p1[2 * i + 1] = exp2f(d1[1]);                                          \
      acc2 += (f32x2){p0[2 * i], p0[2 * i + 1]};                             \
      acc2 += (f32x2){p1[2 * i], p1[2 * i + 1]};                             \
    }                                                                        \
    lsum += acc2[0] + acc2[1];                                               \
    PACK8(p0, 0, pfr[0]);                                                    \
    PACK8(p0, 8, pfr[1]);                                                    \
    PACK8(p1, 0, pfr[2]);                                                    \
    PACK8(p1, 8, pfr[3]);                                                    \
  } while (0)

  f32x16 s0, s1;
  bf16x8 pfr[4];

  // prologue: stage tiles 0,1; compute QK(0), SM(0) -> pfr
  SK(0, 0);
  SV(0, 0);
  __syncthreads();
  SK(1, 64);
  SV(1, 64);
  QK(0);
  SMGEN();

  for (int t = 1; t < 32; ++t) {
    __syncthreads();  // K(t),V(t) landed; V slot (t+1)%3's readers done
    if (t < 31) {
      SK((t + 1) & 1, (t + 1) * 64);
      SV((t + 1) % 3, (t + 1) * 64);
    }
    QK(t & 1);          // MFMA on K(t); independent of PV below
    PVFRAG((t - 1) % 3);  // MFMA on V(t-1) with carried pfr
    SMGEN();            // VALU/exp for tile t; overlaps PV drain
  }
  PVFRAG(31 % 3);  // final PV for tile 31 (V(31) in slot 1)

  // ---- epilogue: lane holds q=ln; d = (r&3)+8*(r>>2)+4*hi (+32 for o1)
  const float inv = 1.0f / xhalf_add(lsum);
  short* orow = ob + (bL + q0 + ln) * 1024 + hd + hi * 4;
#pragma unroll
  for (int g = 0; g < 4; ++g) {
    const unsigned a0 = cvtpk(o0[4 * g + 0] * inv, o0[4 * g + 1] * inv);
    const unsigned a1 = cvtpk(o0[4 * g + 2] * inv, o0[4 * g + 3] * inv);
    *(uint2*)(orow + 8 * g) = make_uint2(a0, a1);
    const unsigned b0 = cvtpk(o1[4 * g + 0] * inv, o1[4 * g + 1] * inv);
    const unsigned b1 = cvtpk(o1[4 * g + 2] * inv, o1[4 * g + 3] * inv);
    *(uint2*)(orow + 32 + 8 * g) = make_uint2(b0, b1);
  }
#undef SMGEN
#undef PACK8
#undef PVFRAG
#undef QK
#undef SV
#undef SK
}

// ---------------------------------------------------------------------------
// Workspace layout (72 MiB): qb, kb, vT, ob: 4 x 16 MiB; wT: 8 MiB.
// Cast scratch aliased into dead regions:
//   qibf -> vT region (dead after gemm_qk, before gemm_vT writes vT)
//   kvbf -> ob region (dead after gemm_vT, before attn writes ob)
// ---------------------------------------------------------------------------
extern "C" void kernel_launch(void* const* d_in, const int* in_sizes, int n_in,
                              void* d_out, int out_size, void* d_ws,
                              size_t ws_size, hipStream_t stream) {
  const size_t ML = (size_t)8192 * 1024;
  short* qb = (short*)d_ws;
  short* kb = qb + ML;
  short* vT = kb + ML;
  short* ob = vT + ML;
  short* wT = ob + ML;  // 4 x 1024x1024 bf16
  short* WqT = wT;
  short* WkT = wT + (size_t)1024 * 1024;
  short* WvT = wT + (size_t)2 * 1024 * 1024;
  short* WoT = wT + (size_t)3 * 1024 * 1024;
  short* qibf = vT;  // aliased cast scratch
  short* kvbf = ob;

  wtrans_kernel<<<dim3(32, 32, 4), 256, 0, stream>>>(
      (const float*)d_in[2], (const float*)d_in[3], (const float*)d_in[4],
      (const float*)d_in[5], wT);

  // both activation casts in one launch
  cast2_kernel<<<dim3(1024, 2), 256, 0, stream>>>(
      (const float*)d_in[0], qibf, (const float*)d_in[1], kvbf,
      (int)(ML / 8));

  // fused q,k projections; q scaled by log2e/8 (softmax in exp2 domain)
  gemm_qk<<<dim3(8, 64, 2), 256, 0, stream>>>(
      qibf, kvbf, WqT, WkT, qb, kb, 0.125f * 1.44269504f);
  // vT = (inputs_kv @ Wv)^T directly: A=WvT [1024][1024], B=kvbf [8192][1024]
  gemm_bb<false, false><<<dim3(64, 8), 256, 0, stream>>>(
      WvT, kvbf, vT, 1024, 8192, 1024, 8192, 1.0f);

  attn8w_kernel<<<dim3(8, 64), 512, 0, stream>>>(qb, kb, vT, ob);

  // out = ob @ Wo (f32 out)
  gemm_bb<true, true><<<dim3(8, 64), 256, 0, stream>>>(
      ob, WoT, d_out, 8192, 1024, 1024, 1024, 1.0f);
}

// Round 17
// 241.066 us; speedup vs baseline: 1.1405x; 1.1405x over previous
//
#include <hip/hip_runtime.h>
#include <hip/hip_bf16.h>

// MultiHeadDotProductAttention: b=4, L=2048, E=1024, H=16, D=64
// R17: attn reverted to R15's proven kernel (T15 refuted twice: R14 spill,
// R16 schedule regression) MINUS s_setprio (T5 prerequisite — wave role
// diversity — absent in 8-wave lockstep; m190 regime). wtrans+casts merged
// into one prep_kernel launch. GEMMs unchanged from R15.

typedef __attribute__((ext_vector_type(8))) short bf16x8;
typedef __attribute__((ext_vector_type(2))) float f32x2;
typedef __attribute__((ext_vector_type(4))) float f32x4;
typedef __attribute__((ext_vector_type(16))) float f32x16;

#define MFMA16(a, b, c) __builtin_amdgcn_mfma_f32_16x16x32_bf16((a), (b), (c), 0, 0, 0)
#define MFMA32(a, b, c) __builtin_amdgcn_mfma_f32_32x32x16_bf16((a), (b), (c), 0, 0, 0)

__device__ __forceinline__ short f2bf(float f) {
  union { float f; unsigned u; } v; v.f = f;
  unsigned r = v.u + 0x7fffu + ((v.u >> 16) & 1u);  // RNE
  return (short)(r >> 16);
}

__device__ __forceinline__ unsigned cvtpk(float lo, float hi) {
  unsigned r;
  asm("v_cvt_pk_bf16_f32 %0, %1, %2" : "=v"(r) : "v"(lo), "v"(hi));
  return r;
}

__device__ __forceinline__ void plswap(unsigned& a, unsigned& b) {
  asm volatile("v_permlane32_swap_b32 %0, %1" : "+v"(a), "+v"(b));
}

// Cross-half (lane i <-> i+32) reduce via the permlane32_swap BUILTIN
// (compiler-managed hazards; opaque-asm version raced a VALU->permlane
// wait-state, R9). Empty-asm pin keeps operand 2 in its own register.
#if __has_builtin(__builtin_amdgcn_permlane32_swap)
typedef __attribute__((ext_vector_type(2))) unsigned u32x2;
__device__ __forceinline__ float xhalf_max(float x) {
  float y = x;
  asm("" : "+v"(y));
  const u32x2 r = __builtin_amdgcn_permlane32_swap(
      __float_as_uint(x), __float_as_uint(y), false, false);
  return fmaxf(__uint_as_float(r[0]), __uint_as_float(r[1]));
}
__device__ __forceinline__ float xhalf_add(float x) {
  float y = x;
  asm("" : "+v"(y));
  const u32x2 r = __builtin_amdgcn_permlane32_swap(
      __float_as_uint(x), __float_as_uint(y), false, false);
  return __uint_as_float(r[0]) + __uint_as_float(r[1]);
}
#else
__device__ __forceinline__ float xhalf_max(float x) {
  float a, b;
  asm volatile(
      "v_mov_b32 %0, %2\n\tv_mov_b32 %1, %2\n\ts_nop 2\n\t"
      "v_permlane32_swap_b32 %0, %1"
      : "=&v"(a), "=&v"(b) : "v"(x));
  return fmaxf(a, b);
}
__device__ __forceinline__ float xhalf_add(float x) {
  float a, b;
  asm volatile(
      "v_mov_b32 %0, %2\n\tv_mov_b32 %1, %2\n\ts_nop 2\n\t"
      "v_permlane32_swap_b32 %0, %1"
      : "=&v"(a), "=&v"(b) : "v"(x));
  return a + b;
}
#endif

__device__ __forceinline__ void gld16(const short* g, short* l) {
  __builtin_amdgcn_global_load_lds(
      (const __attribute__((address_space(1))) unsigned int*)g,
      (__attribute__((address_space(3))) unsigned int*)l, 16, 0, 0);
}

// ---------------------------------------------------------------------------
// Prep: grid (1024,3). y<2: f32->bf16 cast of input y (row-major, RNE).
// y==2: weight transpose W[k][n] f32 -> WT[n][k] bf16, 4 tiles per block.
// ---------------------------------------------------------------------------
__global__ __launch_bounds__(256) void prep_kernel(
    const float* __restrict__ in0, short* __restrict__ out0,
    const float* __restrict__ in1, short* __restrict__ out1, int n8,
    const float* __restrict__ w0, const float* __restrict__ w1,
    const float* __restrict__ w2, const float* __restrict__ w3,
    short* __restrict__ wout) {
  __shared__ float t[32][33];
  if (blockIdx.y < 2) {
    const float* in = blockIdx.y ? in1 : in0;
    short* out = blockIdx.y ? out1 : out0;
    int i = blockIdx.x * 256 + threadIdx.x;
    const int stride = gridDim.x * 256;
    for (; i < n8; i += stride) {
      const float4 f0 = ((const float4*)in)[2 * i];
      const float4 f1 = ((const float4*)in)[2 * i + 1];
      bf16x8 v;
      v[0] = f2bf(f0.x); v[1] = f2bf(f0.y); v[2] = f2bf(f0.z); v[3] = f2bf(f0.w);
      v[4] = f2bf(f1.x); v[5] = f2bf(f1.y); v[6] = f2bf(f1.z); v[7] = f2bf(f1.w);
      ((bf16x8*)out)[i] = v;
    }
  } else {
    const int x = threadIdx.x & 31, y = threadIdx.x >> 5;
#pragma unroll
    for (int tt = 0; tt < 4; ++tt) {
      const int tile = blockIdx.x * 4 + tt;
      const int z = tile >> 10, rr = tile & 1023;
      const int n0 = (rr & 31) * 32, k0 = (rr >> 5) * 32;
      const float* src = (z == 0) ? w0 : (z == 1) ? w1 : (z == 2) ? w2 : w3;
      short* dst = wout + (size_t)z * (1024 * 1024);
      if (tt) __syncthreads();  // LDS reuse guard
#pragma unroll
      for (int yy = y; yy < 32; yy += 8)
        t[yy][x] = src[(size_t)(k0 + yy) * 1024 + n0 + x];
      __syncthreads();
#pragma unroll
      for (int yy = y; yy < 32; yy += 8)
        dst[(size_t)(n0 + yy) * 1024 + k0 + x] = f2bf(t[x][yy]);
    }
  }
}

// ---------------------------------------------------------------------------
// GEMM core (m97 structure), shared by gemm_bb and gemm_qk.
// ---------------------------------------------------------------------------
template <bool OUTF32>
__device__ __forceinline__ void gemm_body(
    const short* __restrict__ A, const short* __restrict__ B,
    void* __restrict__ Cp, int K, int ldc, float scale, int m0, int n0,
    short (*At)[64], short (*Bt)[64]) {
  const int tid = threadIdx.x, l = tid & 63, w = tid >> 6;
  const int wm = (w >> 1) * 64, wn = (w & 1) * 64;
  const short* Abase = A + (size_t)(m0 + w * 8 + (l >> 3)) * K + (l & 7) * 8;
  const short* Bbase = B + (size_t)(n0 + w * 8 + (l >> 3)) * K + (l & 7) * 8;

  f32x4 acc[4][4];
#pragma unroll
  for (int i = 0; i < 4; ++i)
#pragma unroll
    for (int j = 0; j < 4; ++j) acc[i][j] = (f32x4){0.f, 0.f, 0.f, 0.f};

  for (int k0 = 0; k0 < K; k0 += 64) {
    __syncthreads();
#pragma unroll
    for (int i = 0; i < 4; ++i) {
      gld16(Abase + (size_t)i * 32 * K + k0, &At[i * 32 + w * 8][0]);
      gld16(Bbase + (size_t)i * 32 * K + k0, &Bt[i * 32 + w * 8][0]);
    }
    __syncthreads();  // vmcnt(0) before s_barrier -> staged data ready
#pragma unroll
    for (int ks = 0; ks < 2; ++ks) {
      bf16x8 af[4], bfr[4];
#pragma unroll
      for (int mt = 0; mt < 4; ++mt)
        af[mt] = *(const bf16x8*)&At[wm + mt * 16 + (l & 15)][ks * 32 + (l >> 4) * 8];
#pragma unroll
      for (int nt = 0; nt < 4; ++nt)
        bfr[nt] = *(const bf16x8*)&Bt[wn + nt * 16 + (l & 15)][ks * 32 + (l >> 4) * 8];
#pragma unroll
      for (int mt = 0; mt < 4; ++mt)
#pragma unroll
        for (int nt = 0; nt < 4; ++nt)
          acc[mt][nt] = MFMA16(af[mt], bfr[nt], acc[mt][nt]);
    }
  }
  // C/D layout: col = lane&15, row = (lane>>4)*4 + reg (m89)
#pragma unroll
  for (int mt = 0; mt < 4; ++mt)
#pragma unroll
    for (int nt = 0; nt < 4; ++nt)
#pragma unroll
      for (int r = 0; r < 4; ++r) {
        const int row = m0 + wm + mt * 16 + (l >> 4) * 4 + r;
        const int col = n0 + wn + nt * 16 + (l & 15);
        const float v = acc[mt][nt][r] * scale;
        if (OUTF32)
          ((float*)Cp)[(size_t)row * ldc + col] = v;
        else
          ((short*)Cp)[(size_t)row * ldc + col] = f2bf(v);
      }
}

// Generic GEMM (vT and out projections). SWZ: XCD-aware remap.
template <bool OUTF32, bool SWZ>
__global__ __launch_bounds__(256) void gemm_bb(
    const short* __restrict__ A, const short* __restrict__ B,
    void* __restrict__ Cp, int M, int N, int K, int ldc, float scale) {
  __shared__ __align__(16) short At[128][64];
  __shared__ __align__(16) short Bt[128][64];
  int bx = blockIdx.x, by = blockIdx.y;
  if (SWZ) {
    const int nbx = gridDim.x;
    const int lin = by * nbx + bx;
    const int cpx = (nbx * gridDim.y) >> 3;
    const int swz = (lin & 7) * cpx + (lin >> 3);
    bx = swz % nbx;
    by = swz / nbx;
  }
  gemm_body<OUTF32>(A, B, Cp, K, ldc, scale, by * 128, bx * 128, At, Bt);
}

// Fused q+k projections: grid (8,64,2); z=0 -> q (scaled), z=1 -> k.
// XCD swizzle over the full 1024-block grid.
__global__ __launch_bounds__(256) void gemm_qk(
    const short* __restrict__ Aq, const short* __restrict__ Ak,
    const short* __restrict__ Bq, const short* __restrict__ Bk,
    short* __restrict__ Cq, short* __restrict__ Ck, float scaleq) {
  __shared__ __align__(16) short At[128][64];
  __shared__ __align__(16) short Bt[128][64];
  const int lin = (blockIdx.z * 64 + blockIdx.y) * 8 + blockIdx.x;
  const int swz = (lin & 7) * 128 + (lin >> 3);
  const int bz = swz >> 9;  // / 512
  const int rem = swz & 511;
  const int by = rem >> 3, bx = rem & 7;
  const short* A = bz ? Ak : Aq;
  const short* B = bz ? Bk : Bq;
  short* C = bz ? Ck : Cq;
  const float scale = bz ? 1.0f : scaleq;
  gemm_body<false>(A, B, C, 1024, 1024, scale, by * 128, bx * 128, At, Bt);
}

// ---------------------------------------------------------------------------
// Flash attention (R15-proven, setprio removed): 8 waves x 32 q-rows,
// KVBLK=64, defer-max, permlane cross-half reduces, packed-f32 softmax,
// XCD swizzle. qb,kb: [b*2048+l][h*64+d] bf16 (q pre-scaled by log2e/8).
// vT: [h*64+d][b*2048+kv] bf16.  ob: [b*2048+q][h*64+d] bf16.
// ---------------------------------------------------------------------------
__global__ __launch_bounds__(512) void attn8w_kernel(
    const short* __restrict__ qb, const short* __restrict__ kb,
    const short* __restrict__ vT, short* __restrict__ ob) {
  __shared__ __align__(16) short Ksh[2][64][64];
  __shared__ __align__(16) short Vsh[2][64][64];
  const int tid = threadIdx.x, w = tid >> 6, l = tid & 63;
  const int hi = l >> 5, ln = l & 31;
  // T1 swizzle: grid (8,64), nwg=512. XCD k gets bh in [8k, 8k+8).
  const int lin = blockIdx.y * 8 + blockIdx.x;
  const int swz = (lin & 7) * 64 + (lin >> 3);
  const int qc = swz & 7, bh = swz >> 3;
  const int b = bh >> 4, h = bh & 15;
  const size_t bL = (size_t)b * 2048;
  const int hd = h * 64;
  const int q0 = qc * 256 + w * 32;

  // staging: wave w stages rows w*8..w*8+7 of K and of V (1 gld16 each)
  const int sr0 = w * 8 + (l >> 3);
  const int sc0 = ((l & 7) ^ (sr0 & 7)) << 3;  // pre-swizzled source col

#define STAGE(BUF, KV0)                                                    \
  do {                                                                     \
    gld16(kb + (bL + (KV0) + sr0) * 1024 + hd + sc0, &Ksh[BUF][w * 8][0]); \
    gld16(vT + (size_t)(hd + sr0) * 8192 + bL + (KV0) + sc0,               \
          &Vsh[BUF][w * 8][0]);                                            \
  } while (0)

  bf16x8 qf[4];
  {
    const short* qrow = qb + (bL + q0 + ln) * 1024 + hd + hi * 8;
#pragma unroll
    for (int c = 0; c < 4; ++c) qf[c] = *(const bf16x8*)(qrow + c * 16);
  }

  f32x16 o0, o1;
#pragma unroll
  for (int i = 0; i < 16; ++i) { o0[i] = 0.f; o1[i] = 0.f; }
  float m = -1e30f, lsum = 0.f;  // lsum is LANE-PARTIAL (combined at end)

  const int swzk = ln & 7;

  STAGE(0, 0);
  int cur = 0;
  for (int t = 0; t < 32; ++t) {
    __syncthreads();
    if (t < 31) STAGE(cur ^ 1, (t + 1) * 64);

    // ---- S^T = K · Q^T over d chunks
    f32x16 s0, s1;
#pragma unroll
    for (int i = 0; i < 16; ++i) { s0[i] = 0.f; s1[i] = 0.f; }
#pragma unroll
    for (int c = 0; c < 4; ++c) {
      const int bcol = ((((c << 1) | hi)) ^ swzk) << 3;
      const bf16x8 kf0 = *(const bf16x8*)&Ksh[cur][ln][bcol];
      const bf16x8 kf1 = *(const bf16x8*)&Ksh[cur][32 + ln][bcol];
      s0 = MFMA32(kf0, qf[c], s0);
      s1 = MFMA32(kf1, qf[c], s1);
    }

    // ---- online softmax (exp2 domain), lane-local row q = ln.
    f32x2 pm0 = (f32x2){s0[0], s0[1]};
    f32x2 pm1 = (f32x2){s1[0], s1[1]};
#pragma unroll
    for (int i = 1; i < 8; ++i) {
      pm0 = __builtin_elementwise_max(pm0, (f32x2){s0[2 * i], s0[2 * i + 1]});
      pm1 = __builtin_elementwise_max(pm1, (f32x2){s1[2 * i], s1[2 * i + 1]});
    }
    pm0 = __builtin_elementwise_max(pm0, pm1);
    float pmax = fmaxf(pm0[0], pm0[1]);
    pmax = xhalf_max(pmax);

    // defer-max (T13)
    if (!__all(pmax - m <= 8.0f)) {
      const float mnew = fmaxf(m, pmax);
      const float fac = exp2f(m - mnew);  // identical across lane halves
      m = mnew;
      lsum *= fac;
      o0 *= fac;
      o1 *= fac;
    }

    float p0[16], p1[16];
    const f32x2 m2 = (f32x2){m, m};
    f32x2 acc2 = (f32x2){0.f, 0.f};
#pragma unroll
    for (int i = 0; i < 8; ++i) {
      const f32x2 d0 = (f32x2){s0[2 * i], s0[2 * i + 1]} - m2;
      const f32x2 d1 = (f32x2){s1[2 * i], s1[2 * i + 1]} - m2;
      p0[2 * i] = exp2f(d0[0]);
      p0[2 * i + 1] = exp2f(d0[1]);
      p1[2 * i] = exp2f(d1[0]);
      p1[2 * i + 1] = exp2f(d1[1]);
      acc2 += (f32x2){p0[2 * i], p0[2 * i + 1]};
      acc2 += (f32x2){p1[2 * i], p1[2 * i + 1]};
    }
    lsum += acc2[0] + acc2[1];  // lane-partial; cross-half combine at end

    // ---- O^T += V^T · P^T  (P packed in-register via cvt_pk + permlane)
#define PVCHUNK(PARR, BASE, C)                                               \
  do {                                                                       \
    unsigned A0 = cvtpk(PARR[(BASE) + 0], PARR[(BASE) + 1]);                 \
    unsigned A1 = cvtpk(PARR[(BASE) + 2], PARR[(BASE) + 3]);                 \
    unsigned B0 = cvtpk(PARR[(BASE) + 4], PARR[(BASE) + 5]);                 \
    unsigned B1 = cvtpk(PARR[(BASE) + 6], PARR[(BASE) + 7]);                 \
    plswap(A0, B0);                                                          \
    plswap(A1, B1);                                                          \
    union { unsigned u[4]; bf16x8 v; } pf;                                   \
    pf.u[0] = A0; pf.u[1] = A1; pf.u[2] = B0; pf.u[3] = B1;                  \
    const int bcol = ((((C) << 1) | hi) ^ swzk) << 3;                        \
    const bf16x8 vf0 = *(const bf16x8*)&Vsh[cur][ln][bcol];                  \
    const bf16x8 vf1 = *(const bf16x8*)&Vsh[cur][32 + ln][bcol];             \
    o0 = MFMA32(vf0, pf.v, o0);                                              \
    o1 = MFMA32(vf1, pf.v, o1);                                              \
  } while (0)

    PVCHUNK(p0, 0, 0);
    PVCHUNK(p0, 8, 1);
    PVCHUNK(p1, 0, 2);
    PVCHUNK(p1, 8, 3);
#undef PVCHUNK

    cur ^= 1;
  }

  // ---- epilogue: lane holds q=ln; d = (r&3)+8*(r>>2)+4*hi (+32 for o1)
  const float inv = 1.0f / xhalf_add(lsum);
  short* orow = ob + (bL + q0 + ln) * 1024 + hd + hi * 4;
#pragma unroll
  for (int g = 0; g < 4; ++g) {
    const unsigned a0 = cvtpk(o0[4 * g + 0] * inv, o0[4 * g + 1] * inv);
    const unsigned a1 = cvtpk(o0[4 * g + 2] * inv, o0[4 * g + 3] * inv);
    *(uint2*)(orow + 8 * g) = make_uint2(a0, a1);
    const unsigned b0 = cvtpk(o1[4 * g + 0] * inv, o1[4 * g + 1] * inv);
    const unsigned b1 = cvtpk(o1[4 * g + 2] * inv, o1[4 * g + 3] * inv);
    *(uint2*)(orow + 32 + 8 * g) = make_uint2(b0, b1);
  }
#undef STAGE
}

// ---------------------------------------------------------------------------
// Workspace layout (72 MiB): qb, kb, vT, ob: 4 x 16 MiB; wT: 8 MiB.
// Cast scratch aliased into dead regions:
//   qibf -> vT region (dead after gemm_qk, before gemm_vT writes vT)
//   kvbf -> ob region (dead after gemm_vT, before attn writes ob)
// ---------------------------------------------------------------------------
extern "C" void kernel_launch(void* const* d_in, const int* in_sizes, int n_in,
                              void* d_out, int out_size, void* d_ws,
                              size_t ws_size, hipStream_t stream) {
  const size_t ML = (size_t)8192 * 1024;
  short* qb = (short*)d_ws;
  short* kb = qb + ML;
  short* vT = kb + ML;
  short* ob = vT + ML;
  short* wT = ob + ML;  // 4 x 1024x1024 bf16
  short* WqT = wT;
  short* WkT = wT + (size_t)1024 * 1024;
  short* WvT = wT + (size_t)2 * 1024 * 1024;
  short* WoT = wT + (size_t)3 * 1024 * 1024;
  short* qibf = vT;  // aliased cast scratch
  short* kvbf = ob;

  // casts (y<2) + weight transpose (y==2) in one launch
  prep_kernel<<<dim3(1024, 3), 256, 0, stream>>>(
      (const float*)d_in[0], qibf, (const float*)d_in[1], kvbf, (int)(ML / 8),
      (const float*)d_in[2], (const float*)d_in[3], (const float*)d_in[4],
      (const float*)d_in[5], wT);

  // fused q,k projections; q scaled by log2e/8 (softmax in exp2 domain)
  gemm_qk<<<dim3(8, 64, 2), 256, 0, stream>>>(
      qibf, kvbf, WqT, WkT, qb, kb, 0.125f * 1.44269504f);
  // vT = (inputs_kv @ Wv)^T directly: A=WvT [1024][1024], B=kvbf [8192][1024]
  gemm_bb<false, false><<<dim3(64, 8), 256, 0, stream>>>(
      WvT, kvbf, vT, 1024, 8192, 1024, 8192, 1.0f);

  attn8w_kernel<<<dim3(8, 64), 512, 0, stream>>>(qb, kb, vT, ob);

  // out = ob @ Wo (f32 out)
  gemm_bb<true, true><<<dim3(8, 64), 256, 0, stream>>>(
      ob, WoT, d_out, 8192, 1024, 1024, 1024, 1.0f);
}

// Round 18
// 240.804 us; speedup vs baseline: 1.1418x; 1.0011x over previous
//
#include <hip/hip_runtime.h>
#include <hip/hip_bf16.h>

// MultiHeadDotProductAttention: b=4, L=2048, E=1024, H=16, D=64
// R17: attn reverted to R15's proven kernel (T15 refuted twice: R14 spill,
// R16 schedule regression) MINUS s_setprio (T5 prerequisite — wave role
// diversity — absent in 8-wave lockstep; m190 regime). wtrans+casts merged
// into one prep_kernel launch. GEMMs unchanged from R15.

typedef __attribute__((ext_vector_type(8))) short bf16x8;
typedef __attribute__((ext_vector_type(2))) float f32x2;
typedef __attribute__((ext_vector_type(4))) float f32x4;
typedef __attribute__((ext_vector_type(16))) float f32x16;

#define MFMA16(a, b, c) __builtin_amdgcn_mfma_f32_16x16x32_bf16((a), (b), (c), 0, 0, 0)
#define MFMA32(a, b, c) __builtin_amdgcn_mfma_f32_32x32x16_bf16((a), (b), (c), 0, 0, 0)

__device__ __forceinline__ short f2bf(float f) {
  union { float f; unsigned u; } v; v.f = f;
  unsigned r = v.u + 0x7fffu + ((v.u >> 16) & 1u);  // RNE
  return (short)(r >> 16);
}

__device__ __forceinline__ unsigned cvtpk(float lo, float hi) {
  unsigned r;
  asm("v_cvt_pk_bf16_f32 %0, %1, %2" : "=v"(r) : "v"(lo), "v"(hi));
  return r;
}

__device__ __forceinline__ void plswap(unsigned& a, unsigned& b) {
  asm volatile("v_permlane32_swap_b32 %0, %1" : "+v"(a), "+v"(b));
}

// Cross-half (lane i <-> i+32) reduce via the permlane32_swap BUILTIN
// (compiler-managed hazards; opaque-asm version raced a VALU->permlane
// wait-state, R9). Empty-asm pin keeps operand 2 in its own register.
#if __has_builtin(__builtin_amdgcn_permlane32_swap)
typedef __attribute__((ext_vector_type(2))) unsigned u32x2;
__device__ __forceinline__ float xhalf_max(float x) {
  float y = x;
  asm("" : "+v"(y));
  const u32x2 r = __builtin_amdgcn_permlane32_swap(
      __float_as_uint(x), __float_as_uint(y), false, false);
  return fmaxf(__uint_as_float(r[0]), __uint_as_float(r[1]));
}
__device__ __forceinline__ float xhalf_add(float x) {
  float y = x;
  asm("" : "+v"(y));
  const u32x2 r = __builtin_amdgcn_permlane32_swap(
      __float_as_uint(x), __float_as_uint(y), false, false);
  return __uint_as_float(r[0]) + __uint_as_float(r[1]);
}
#else
__device__ __forceinline__ float xhalf_max(float x) {
  float a, b;
  asm volatile(
      "v_mov_b32 %0, %2\n\tv_mov_b32 %1, %2\n\ts_nop 2\n\t"
      "v_permlane32_swap_b32 %0, %1"
      : "=&v"(a), "=&v"(b) : "v"(x));
  return fmaxf(a, b);
}
__device__ __forceinline__ float xhalf_add(float x) {
  float a, b;
  asm volatile(
      "v_mov_b32 %0, %2\n\tv_mov_b32 %1, %2\n\ts_nop 2\n\t"
      "v_permlane32_swap_b32 %0, %1"
      : "=&v"(a), "=&v"(b) : "v"(x));
  return a + b;
}
#endif

__device__ __forceinline__ void gld16(const short* g, short* l) {
  __builtin_amdgcn_global_load_lds(
      (const __attribute__((address_space(1))) unsigned int*)g,
      (__attribute__((address_space(3))) unsigned int*)l, 16, 0, 0);
}

// ---------------------------------------------------------------------------
// Prep: grid (1024,3). y<2: f32->bf16 cast of input y (row-major, RNE).
// y==2: weight transpose W[k][n] f32 -> WT[n][k] bf16, 4 tiles per block.
// ---------------------------------------------------------------------------
__global__ __launch_bounds__(256) void prep_kernel(
    const float* __restrict__ in0, short* __restrict__ out0,
    const float* __restrict__ in1, short* __restrict__ out1, int n8,
    const float* __restrict__ w0, const float* __restrict__ w1,
    const float* __restrict__ w2, const float* __restrict__ w3,
    short* __restrict__ wout) {
  __shared__ float t[32][33];
  if (blockIdx.y < 2) {
    const float* in = blockIdx.y ? in1 : in0;
    short* out = blockIdx.y ? out1 : out0;
    int i = blockIdx.x * 256 + threadIdx.x;
    const int stride = gridDim.x * 256;
    for (; i < n8; i += stride) {
      const float4 f0 = ((const float4*)in)[2 * i];
      const float4 f1 = ((const float4*)in)[2 * i + 1];
      bf16x8 v;
      v[0] = f2bf(f0.x); v[1] = f2bf(f0.y); v[2] = f2bf(f0.z); v[3] = f2bf(f0.w);
      v[4] = f2bf(f1.x); v[5] = f2bf(f1.y); v[6] = f2bf(f1.z); v[7] = f2bf(f1.w);
      ((bf16x8*)out)[i] = v;
    }
  } else {
    const int x = threadIdx.x & 31, y = threadIdx.x >> 5;
#pragma unroll
    for (int tt = 0; tt < 4; ++tt) {
      const int tile = blockIdx.x * 4 + tt;
      const int z = tile >> 10, rr = tile & 1023;
      const int n0 = (rr & 31) * 32, k0 = (rr >> 5) * 32;
      const float* src = (z == 0) ? w0 : (z == 1) ? w1 : (z == 2) ? w2 : w3;
      short* dst = wout + (size_t)z * (1024 * 1024);
      if (tt) __syncthreads();  // LDS reuse guard
#pragma unroll
      for (int yy = y; yy < 32; yy += 8)
        t[yy][x] = src[(size_t)(k0 + yy) * 1024 + n0 + x];
      __syncthreads();
#pragma unroll
      for (int yy = y; yy < 32; yy += 8)
        dst[(size_t)(n0 + yy) * 1024 + k0 + x] = f2bf(t[x][yy]);
    }
  }
}

// ---------------------------------------------------------------------------
// GEMM core (m97 structure), shared by gemm_bb and gemm_qk.
// ---------------------------------------------------------------------------
template <bool OUTF32>
__device__ __forceinline__ void gemm_body(
    const short* __restrict__ A, const short* __restrict__ B,
    void* __restrict__ Cp, int K, int ldc, float scale, int m0, int n0,
    short (*At)[64], short (*Bt)[64]) {
  const int tid = threadIdx.x, l = tid & 63, w = tid >> 6;
  const int wm = (w >> 1) * 64, wn = (w & 1) * 64;
  const short* Abase = A + (size_t)(m0 + w * 8 + (l >> 3)) * K + (l & 7) * 8;
  const short* Bbase = B + (size_t)(n0 + w * 8 + (l >> 3)) * K + (l & 7) * 8;

  f32x4 acc[4][4];
#pragma unroll
  for (int i = 0; i < 4; ++i)
#pragma unroll
    for (int j = 0; j < 4; ++j) acc[i][j] = (f32x4){0.f, 0.f, 0.f, 0.f};

  for (int k0 = 0; k0 < K; k0 += 64) {
    __syncthreads();
#pragma unroll
    for (int i = 0; i < 4; ++i) {
      gld16(Abase + (size_t)i * 32 * K + k0, &At[i * 32 + w * 8][0]);
      gld16(Bbase + (size_t)i * 32 * K + k0, &Bt[i * 32 + w * 8][0]);
    }
    __syncthreads();  // vmcnt(0) before s_barrier -> staged data ready
#pragma unroll
    for (int ks = 0; ks < 2; ++ks) {
      bf16x8 af[4], bfr[4];
#pragma unroll
      for (int mt = 0; mt < 4; ++mt)
        af[mt] = *(const bf16x8*)&At[wm + mt * 16 + (l & 15)][ks * 32 + (l >> 4) * 8];
#pragma unroll
      for (int nt = 0; nt < 4; ++nt)
        bfr[nt] = *(const bf16x8*)&Bt[wn + nt * 16 + (l & 15)][ks * 32 + (l >> 4) * 8];
#pragma unroll
      for (int mt = 0; mt < 4; ++mt)
#pragma unroll
        for (int nt = 0; nt < 4; ++nt)
          acc[mt][nt] = MFMA16(af[mt], bfr[nt], acc[mt][nt]);
    }
  }
  // C/D layout: col = lane&15, row = (lane>>4)*4 + reg (m89)
#pragma unroll
  for (int mt = 0; mt < 4; ++mt)
#pragma unroll
    for (int nt = 0; nt < 4; ++nt)
#pragma unroll
      for (int r = 0; r < 4; ++r) {
        const int row = m0 + wm + mt * 16 + (l >> 4) * 4 + r;
        const int col = n0 + wn + nt * 16 + (l & 15);
        const float v = acc[mt][nt][r] * scale;
        if (OUTF32)
          ((float*)Cp)[(size_t)row * ldc + col] = v;
        else
          ((short*)Cp)[(size_t)row * ldc + col] = f2bf(v);
      }
}

// Generic GEMM (vT and out projections). SWZ: XCD-aware remap.
template <bool OUTF32, bool SWZ>
__global__ __launch_bounds__(256) void gemm_bb(
    const short* __restrict__ A, const short* __restrict__ B,
    void* __restrict__ Cp, int M, int N, int K, int ldc, float scale) {
  __shared__ __align__(16) short At[128][64];
  __shared__ __align__(16) short Bt[128][64];
  int bx = blockIdx.x, by = blockIdx.y;
  if (SWZ) {
    const int nbx = gridDim.x;
    const int lin = by * nbx + bx;
    const int cpx = (nbx * gridDim.y) >> 3;
    const int swz = (lin & 7) * cpx + (lin >> 3);
    bx = swz % nbx;
    by = swz / nbx;
  }
  gemm_body<OUTF32>(A, B, Cp, K, ldc, scale, by * 128, bx * 128, At, Bt);
}

// Fused q+k projections: grid (8,64,2); z=0 -> q (scaled), z=1 -> k.
// XCD swizzle over the full 1024-block grid.
__global__ __launch_bounds__(256) void gemm_qk(
    const short* __restrict__ Aq, const short* __restrict__ Ak,
    const short* __restrict__ Bq, const short* __restrict__ Bk,
    short* __restrict__ Cq, short* __restrict__ Ck, float scaleq) {
  __shared__ __align__(16) short At[128][64];
  __shared__ __align__(16) short Bt[128][64];
  const int lin = (blockIdx.z * 64 + blockIdx.y) * 8 + blockIdx.x;
  const int swz = (lin & 7) * 128 + (lin >> 3);
  const int bz = swz >> 9;  // / 512
  const int rem = swz & 511;
  const int by = rem >> 3, bx = rem & 7;
  const short* A = bz ? Ak : Aq;
  const short* B = bz ? Bk : Bq;
  short* C = bz ? Ck : Cq;
  const float scale = bz ? 1.0f : scaleq;
  gemm_body<false>(A, B, C, 1024, 1024, scale, by * 128, bx * 128, At, Bt);
}

// ---------------------------------------------------------------------------
// Flash attention (R15-proven, setprio removed): 8 waves x 32 q-rows,
// KVBLK=64, defer-max, permlane cross-half reduces, packed-f32 softmax,
// XCD swizzle. qb,kb: [b*2048+l][h*64+d] bf16 (q pre-scaled by log2e/8).
// vT: [h*64+d][b*2048+kv] bf16.  ob: [b*2048+q][h*64+d] bf16.
// ---------------------------------------------------------------------------
__global__ __launch_bounds__(512) void attn8w_kernel(
    const short* __restrict__ qb, const short* __restrict__ kb,
    const short* __restrict__ vT, short* __restrict__ ob) {
  __shared__ __align__(16) short Ksh[2][64][64];
  __shared__ __align__(16) short Vsh[2][64][64];
  const int tid = threadIdx.x, w = tid >> 6, l = tid & 63;
  const int hi = l >> 5, ln = l & 31;
  // T1 swizzle: grid (8,64), nwg=512. XCD k gets bh in [8k, 8k+8).
  const int lin = blockIdx.y * 8 + blockIdx.x;
  const int swz = (lin & 7) * 64 + (lin >> 3);
  const int qc = swz & 7, bh = swz >> 3;
  const int b = bh >> 4, h = bh & 15;
  const size_t bL = (size_t)b * 2048;
  const int hd = h * 64;
  const int q0 = qc * 256 + w * 32;

  // staging: wave w stages rows w*8..w*8+7 of K and of V (1 gld16 each)
  const int sr0 = w * 8 + (l >> 3);
  const int sc0 = ((l & 7) ^ (sr0 & 7)) << 3;  // pre-swizzled source col

#define STAGE(BUF, KV0)                                                    \
  do {                                                                     \
    gld16(kb + (bL + (KV0) + sr0) * 1024 + hd + sc0, &Ksh[BUF][w * 8][0]); \
    gld16(vT + (size_t)(hd + sr0) * 8192 + bL + (KV0) + sc0,               \
          &Vsh[BUF][w * 8][0]);                                            \
  } while (0)

  bf16x8 qf[4];
  {
    const short* qrow = qb + (bL + q0 + ln) * 1024 + hd + hi * 8;
#pragma unroll
    for (int c = 0; c < 4; ++c) qf[c] = *(const bf16x8*)(qrow + c * 16);
  }

  f32x16 o0, o1;
#pragma unroll
  for (int i = 0; i < 16; ++i) { o0[i] = 0.f; o1[i] = 0.f; }
  float m = -1e30f, lsum = 0.f;  // lsum is LANE-PARTIAL (combined at end)

  const int swzk = ln & 7;

  STAGE(0, 0);
  int cur = 0;
  for (int t = 0; t < 32; ++t) {
    __syncthreads();
    if (t < 31) STAGE(cur ^ 1, (t + 1) * 64);

    // ---- S^T = K · Q^T over d chunks
    f32x16 s0, s1;
#pragma unroll
    for (int i = 0; i < 16; ++i) { s0[i] = 0.f; s1[i] = 0.f; }
#pragma unroll
    for (int c = 0; c < 4; ++c) {
      const int bcol = ((((c << 1) | hi)) ^ swzk) << 3;
      const bf16x8 kf0 = *(const bf16x8*)&Ksh[cur][ln][bcol];
      const bf16x8 kf1 = *(const bf16x8*)&Ksh[cur][32 + ln][bcol];
      s0 = MFMA32(kf0, qf[c], s0);
      s1 = MFMA32(kf1, qf[c], s1);
    }

    // ---- online softmax (exp2 domain), lane-local row q = ln.
    f32x2 pm0 = (f32x2){s0[0], s0[1]};
    f32x2 pm1 = (f32x2){s1[0], s1[1]};
#pragma unroll
    for (int i = 1; i < 8; ++i) {
      pm0 = __builtin_elementwise_max(pm0, (f32x2){s0[2 * i], s0[2 * i + 1]});
      pm1 = __builtin_elementwise_max(pm1, (f32x2){s1[2 * i], s1[2 * i + 1]});
    }
    pm0 = __builtin_elementwise_max(pm0, pm1);
    float pmax = fmaxf(pm0[0], pm0[1]);
    pmax = xhalf_max(pmax);

    // defer-max (T13)
    if (!__all(pmax - m <= 8.0f)) {
      const float mnew = fmaxf(m, pmax);
      const float fac = exp2f(m - mnew);  // identical across lane halves
      m = mnew;
      lsum *= fac;
      o0 *= fac;
      o1 *= fac;
    }

    float p0[16], p1[16];
    const f32x2 m2 = (f32x2){m, m};
    f32x2 acc2 = (f32x2){0.f, 0.f};
#pragma unroll
    for (int i = 0; i < 8; ++i) {
      const f32x2 d0 = (f32x2){s0[2 * i], s0[2 * i + 1]} - m2;
      const f32x2 d1 = (f32x2){s1[2 * i], s1[2 * i + 1]} - m2;
      p0[2 * i] = exp2f(d0[0]);
      p0[2 * i + 1] = exp2f(d0[1]);
      p1[2 * i] = exp2f(d1[0]);
      p1[2 * i + 1] = exp2f(d1[1]);
      acc2 += (f32x2){p0[2 * i], p0[2 * i + 1]};
      acc2 += (f32x2){p1[2 * i], p1[2 * i + 1]};
    }
    lsum += acc2[0] + acc2[1];  // lane-partial; cross-half combine at end

    // ---- O^T += V^T · P^T  (P packed in-register via cvt_pk + permlane)
#define PVCHUNK(PARR, BASE, C)                                               \
  do {                                                                       \
    unsigned A0 = cvtpk(PARR[(BASE) + 0], PARR[(BASE) + 1]);                 \
    unsigned A1 = cvtpk(PARR[(BASE) + 2], PARR[(BASE) + 3]);                 \
    unsigned B0 = cvtpk(PARR[(BASE) + 4], PARR[(BASE) + 5]);                 \
    unsigned B1 = cvtpk(PARR[(BASE) + 6], PARR[(BASE) + 7]);                 \
    plswap(A0, B0);                                                          \
    plswap(A1, B1);                                                          \
    union { unsigned u[4]; bf16x8 v; } pf;                                   \
    pf.u[0] = A0; pf.u[1] = A1; pf.u[2] = B0; pf.u[3] = B1;                  \
    const int bcol = ((((C) << 1) | hi) ^ swzk) << 3;                        \
    const bf16x8 vf0 = *(const bf16x8*)&Vsh[cur][ln][bcol];                  \
    const bf16x8 vf1 = *(const bf16x8*)&Vsh[cur][32 + ln][bcol];             \
    o0 = MFMA32(vf0, pf.v, o0);                                              \
    o1 = MFMA32(vf1, pf.v, o1);                                              \
  } while (0)

    PVCHUNK(p0, 0, 0);
    PVCHUNK(p0, 8, 1);
    PVCHUNK(p1, 0, 2);
    PVCHUNK(p1, 8, 3);
#undef PVCHUNK

    cur ^= 1;
  }

  // ---- epilogue: lane holds q=ln; d = (r&3)+8*(r>>2)+4*hi (+32 for o1)
  const float inv = 1.0f / xhalf_add(lsum);
  short* orow = ob + (bL + q0 + ln) * 1024 + hd + hi * 4;
#pragma unroll
  for (int g = 0; g < 4; ++g) {
    const unsigned a0 = cvtpk(o0[4 * g + 0] * inv, o0[4 * g + 1] * inv);
    const unsigned a1 = cvtpk(o0[4 * g + 2] * inv, o0[4 * g + 3] * inv);
    *(uint2*)(orow + 8 * g) = make_uint2(a0, a1);
    const unsigned b0 = cvtpk(o1[4 * g + 0] * inv, o1[4 * g + 1] * inv);
    const unsigned b1 = cvtpk(o1[4 * g + 2] * inv, o1[4 * g + 3] * inv);
    *(uint2*)(orow + 32 + 8 * g) = make_uint2(b0, b1);
  }
#undef STAGE
}

// ---------------------------------------------------------------------------
// Workspace layout (72 MiB): qb, kb, vT, ob: 4 x 16 MiB; wT: 8 MiB.
// Cast scratch aliased into dead regions:
//   qibf -> vT region (dead after gemm_qk, before gemm_vT writes vT)
//   kvbf -> ob region (dead after gemm_vT, before attn writes ob)
// ---------------------------------------------------------------------------
extern "C" void kernel_launch(void* const* d_in, const int* in_sizes, int n_in,
                              void* d_out, int out_size, void* d_ws,
                              size_t ws_size, hipStream_t stream) {
  const size_t ML = (size_t)8192 * 1024;
  short* qb = (short*)d_ws;
  short* kb = qb + ML;
  short* vT = kb + ML;
  short* ob = vT + ML;
  short* wT = ob + ML;  // 4 x 1024x1024 bf16
  short* WqT = wT;
  short* WkT = wT + (size_t)1024 * 1024;
  short* WvT = wT + (size_t)2 * 1024 * 1024;
  short* WoT = wT + (size_t)3 * 1024 * 1024;
  short* qibf = vT;  // aliased cast scratch
  short* kvbf = ob;

  // casts (y<2) + weight transpose (y==2) in one launch
  prep_kernel<<<dim3(1024, 3), 256, 0, stream>>>(
      (const float*)d_in[0], qibf, (const float*)d_in[1], kvbf, (int)(ML / 8),
      (const float*)d_in[2], (const float*)d_in[3], (const float*)d_in[4],
      (const float*)d_in[5], wT);

  // fused q,k projections; q scaled by log2e/8 (softmax in exp2 domain)
  gemm_qk<<<dim3(8, 64, 2), 256, 0, stream>>>(
      qibf, kvbf, WqT, WkT, qb, kb, 0.125f * 1.44269504f);
  // vT = (inputs_kv @ Wv)^T directly: A=WvT [1024][1024], B=kvbf [8192][1024]
  gemm_bb<false, false><<<dim3(64, 8), 256, 0, stream>>>(
      WvT, kvbf, vT, 1024, 8192, 1024, 8192, 1.0f);

  attn8w_kernel<<<dim3(8, 64), 512, 0, stream>>>(qb, kb, vT, ob);

  // out = ob @ Wo (f32 out)
  gemm_bb<true, true><<<dim3(8, 64), 256, 0, stream>>>(
      ob, WoT, d_out, 8192, 1024, 1024, 1024, 1.0f);
}